// Round 1
// baseline (206.784 us; speedup 1.0000x reference)
//
#include <hip/hip_runtime.h>

// YOLO-v1-style loss, exact port of the JAX reference.
// S=7, B=2, C=20, channels per cell = 30:
//   ch 0..19  : class scores
//   ch 20..24 : box0 x,y,w,h,conf
//   ch 25..29 : box1 x,y,w,h,conf
// cls part of the loss uses channels [5*B: i.e. 10..29] (reference quirk, kept).
//
// R4: coalesced LDS staging via global_load_lds (width=16).
// R3's per-cell float2 direct loads have a 120-B inter-lane stride -> each
// wave VMEM instruction touches ~64 distinct cache lines (64 serialized line
// requests). Counters: 16% HBM, 11% VALU, 0 MFMA -> request-amplification
// bound, not roofline. Fix: each block stages its 256 cells' contiguous
// 30,720-B region per tensor with global_load_lds dwordx4 bursts (1 KiB per
// wave instruction), then reads channels 10..29 per cell from LDS.
// Two-phase (p then a) keeps LDS at 30,736 B -> 5 blocks/CU = 20 waves/CU.
// LDS reads are stride-120 (4-way bank conflict, 1.58x on ~0.4us of LDS
// traffic) -- hidden under the HBM stream; both-sides swizzle not worth it.

#define CH    30
#define EPSL  1e-6f
#define TPB   256
#define REGION_F   (TPB * CH)       // 7680 floats staged per tensor per block
#define REGION_F4  (REGION_F / 4)   // 1920 float4s

typedef const __attribute__((address_space(1))) void* gas_ptr;
typedef __attribute__((address_space(3))) void* las_ptr;

__device__ __forceinline__ float sgnf(float x) {
    return (x > 0.0f) ? 1.0f : ((x < 0.0f) ? -1.0f : 0.0f);
}

__global__ __launch_bounds__(TPB, 5) void yolo_loss_kernel(const float* __restrict__ p,
                                                           const float* __restrict__ a,
                                                           float* __restrict__ out,
                                                           long long n_cells) {
    __shared__ float lds[REGION_F];
    __shared__ float wsum[TPB / 64];

    const int tid  = threadIdx.x;
    const int wid  = tid >> 6;
    const int lane = tid & 63;
    const long long cell0 = (long long)blockIdx.x * TPB;
    const long long cell  = cell0 + tid;
    const bool full   = (cell0 + TPB) <= n_cells;   // block-uniform
    const bool active = cell < n_cells;

    float pd[20], ad[20];
    float lsum = 0.0f;

    if (full) {
        // ---- phase 1: stage p's region, coalesced global->LDS ----
        {
            const float* gbase = p + cell0 * CH;
#pragma unroll
            for (int k = 0; k < 8; ++k) {
                const int b4 = k * TPB + wid * 64;   // wave-uniform float4 base
                if (b4 < REGION_F4) {                // wave-uniform condition
                    __builtin_amdgcn_global_load_lds(
                        (gas_ptr)(gbase + (size_t)(b4 + lane) * 4),
                        (las_ptr)(lds + (size_t)b4 * 4),
                        16, 0, 0);
                }
            }
        }
        __syncthreads();   // vmcnt(0) drain + barrier: p staged
#pragma unroll
        for (int i = 0; i < 10; ++i) {
            const float2 v = *(const float2*)(lds + tid * CH + 10 + 2 * i);
            pd[2 * i] = v.x; pd[2 * i + 1] = v.y;
        }
        __syncthreads();   // all p-reads landed before overwrite

        // ---- phase 2: stage a's region into the same buffer ----
        {
            const float* gbase = a + cell0 * CH;
#pragma unroll
            for (int k = 0; k < 8; ++k) {
                const int b4 = k * TPB + wid * 64;
                if (b4 < REGION_F4) {
                    __builtin_amdgcn_global_load_lds(
                        (gas_ptr)(gbase + (size_t)(b4 + lane) * 4),
                        (las_ptr)(lds + (size_t)b4 * 4),
                        16, 0, 0);
                }
            }
        }
        __syncthreads();   // a staged
#pragma unroll
        for (int i = 0; i < 10; ++i) {
            const float2 v = *(const float2*)(lds + tid * CH + 10 + 2 * i);
            ad[2 * i] = v.x; ad[2 * i + 1] = v.y;
        }
    } else if (active) {
        // tail block (never hit at N=16384: 802816 cells = 3136*256 exact):
        // original strided direct loads.
        const float2* cp2 = (const float2*)(p + cell * CH + 10);
        const float2* ca2 = (const float2*)(a + cell * CH + 10);
#pragma unroll
        for (int i = 0; i < 10; ++i) {
            const float2 v = cp2[i];
            pd[2 * i] = v.x; pd[2 * i + 1] = v.y;
        }
#pragma unroll
        for (int i = 0; i < 10; ++i) {
            const float2 v = ca2[i];
            ad[2 * i] = v.x; ad[2 * i + 1] = v.y;
        }
    }

    if (active) {
        // box attrs: channel 20+5b+i -> index 10+5b+i
        float pxv[2], pyv[2], pwv[2], phv[2], pcv[2];
        float axv[2], ayv[2], awv[2], ahv[2];
#pragma unroll
        for (int b = 0; b < 2; ++b) {
            pxv[b] = pd[10 + 5 * b]; pyv[b] = pd[11 + 5 * b];
            pwv[b] = pd[12 + 5 * b]; phv[b] = pd[13 + 5 * b];
            pcv[b] = pd[14 + 5 * b];
            axv[b] = ad[10 + 5 * b]; ayv[b] = ad[11 + 5 * b];
            awv[b] = ad[12 + 5 * b]; ahv[b] = ad[13 + 5 * b];
        }
        const bool obj = ad[14] > 0.0f;   // a's box-0 conf (channel 24)

        // ---- pairwise IoU, max over target boxes ----
        float miou[2];
#pragma unroll
        for (int pb = 0; pb < 2; ++pb) {
            const float p_tlx = pxv[pb] - 0.5f * pwv[pb];
            const float p_tly = pyv[pb] - 0.5f * phv[pb];
            const float p_brx = pxv[pb] + 0.5f * pwv[pb];
            const float p_bry = pyv[pb] + 0.5f * phv[pb];
            const float p_area = pwv[pb] * phv[pb];
            float best = -3.4e38f;
#pragma unroll
            for (int ab = 0; ab < 2; ++ab) {
                const float a_tlx = axv[ab] - 0.5f * awv[ab];
                const float a_tly = ayv[ab] - 0.5f * ahv[ab];
                const float a_brx = axv[ab] + 0.5f * awv[ab];
                const float a_bry = ayv[ab] + 0.5f * ahv[ab];
                float sx = fminf(p_brx, a_brx) - fmaxf(p_tlx, a_tlx);
                float sy = fminf(p_bry, a_bry) - fmaxf(p_tly, a_tly);
                sx = fmaxf(sx, 0.0f);
                sy = fmaxf(sy, 0.0f);
                const float inter = sx * sy;
                const float uni = p_area + awv[ab] * ahv[ab] - inter;
                const float iou = (uni == 0.0f) ? 0.0f : (inter / uni);  // where(zero,0)/where(zero,eps)
                best = fmaxf(best, iou);
            }
            miou[pb] = best;
        }
        // argmax over pred boxes, first-max tie-break (jnp.argmax semantics)
        const int resp = (miou[1] > miou[0]) ? 1 : 0;

        // ---- coordinate / confidence losses ----
#pragma unroll
        for (int b = 0; b < 2; ++b) {
            const bool oij = obj && (b == resp);
            if (oij) {
                const float dx = axv[b] - pxv[b];
                const float dy = ayv[b] - pyv[b];
                const float dw = sgnf(awv[b]) * sqrtf(awv[b] + EPSL) - sgnf(pwv[b]) * sqrtf(pwv[b] + EPSL);
                const float dh = sgnf(ahv[b]) * sqrtf(ahv[b] + EPSL) - sgnf(phv[b]) * sqrtf(phv[b] + EPSL);
                const float dc = 1.0f - pcv[b];  // (obj_ij^2 - obj_ij*pc)^2 with obj_ij==1
                lsum += 5.0f * (dx * dx + dy * dy + dw * dw + dh * dh) + dc * dc;
            } else {
                // noobj term: (noobj_ij*obj_ij - noobj_ij*pc)^2 = pc^2 when obj_ij==0
                lsum += 0.5f * pcv[b] * pcv[b];
            }
        }

        // ---- "class" loss over channels 10..29 (indices 0..19), gated by obj_i ----
        if (obj) {
#pragma unroll
            for (int k = 0; k < 20; ++k) {
                const float d = pd[k] - ad[k];
                lsum += d * d;
            }
        }
    }

    // ---- reduction: wave shfl -> LDS -> one atomic per block ----
    float v = lsum;
#pragma unroll
    for (int off = 32; off > 0; off >>= 1)
        v += __shfl_down(v, off, 64);
    if ((tid & 63) == 0) wsum[tid >> 6] = v;
    __syncthreads();
    if (tid == 0) {
        float t = 0.0f;
#pragma unroll
        for (int w = 0; w < TPB / 64; ++w) t += wsum[w];
        atomicAdd(out, t);
    }
}

extern "C" void kernel_launch(void* const* d_in, const int* in_sizes, int n_in,
                              void* d_out, int out_size, void* d_ws, size_t ws_size,
                              hipStream_t stream) {
    const float* p = (const float*)d_in[0];
    const float* a = (const float*)d_in[1];
    float* out = (float*)d_out;

    const long long n_cells = (long long)in_sizes[0] / CH;   // 16384*7*7 = 802816
    const int grid = (int)((n_cells + TPB - 1) / TPB);       // 3136, exact

    // d_out is re-poisoned (0xAA) before every timed replay -> must zero it here.
    hipMemsetAsync(d_out, 0, sizeof(float), stream);
    yolo_loss_kernel<<<grid, TPB, 0, stream>>>(p, a, out, n_cells);
}